// Round 19
// baseline (226.385 us; speedup 1.0000x reference)
//
#include <hip/hip_runtime.h>
#include <hip/hip_bf16.h>

#define NTH     256
#define ROWS    32
#define NSTEPS  100
#define PITERS  50
#define LAMBDAV 0.1f

typedef __bf16 bf16x8 __attribute__((ext_vector_type(8)));
typedef float  f32x4  __attribute__((ext_vector_type(4)));

// R19 = R18 + p2 W-hi fragments back in REGISTERS (w2h[4][2], R14 layout),
// WH LDS plane deleted. R15 bundled "WH->LDS" with the pow-spill fix and the
// placement was never isolated; at VGPR=96 there is headroom (2 waves/SIMD =
// 256-reg budget). p2 LDS reads 12->4 b128/wave-step; LDS 53.5K -> 20.7K.
// Numerics bit-identical to R18: absmax must be exactly 0.06640625.
// LDS map (20736 B):
//   YH bf16 [32][256] @0     (16384) stride 512
//   RH bf16 [32][64]  @16384 (4096)  stride 128
//   v  fp32 [64]      @20480 (256)
//   init overlays: WC/M fp32 [64][64] @0 (16384, inside YH; dead before YH use)
// Persistent regs ~136: wbh 32 + w2h 32 + xm 32 + ym 32 + nin 8.
#define YHo 0
#define RHo 16384
#define Vo  20480
#define WCo 0
#define Mo  0

__global__ __launch_bounds__(NTH, 2)
void fista19(const float* __restrict__ inp, const float* __restrict__ Wg,
             const float* __restrict__ X0, float* __restrict__ out)
{
    __shared__ __align__(16) char lds[20736];
    __shared__ float scal[2];

    const int tid  = threadIdx.x;
    const int w    = tid >> 6;        // 0..3
    const int lane = tid & 63;
    const int l4   = lane >> 4;       // 0..3
    const int ln   = lane & 15;       // 0..15
    const int rb   = blockIdx.x * ROWS;
    const int rxl  = (ln & 7) << 4;

    // ================= M = W^T W  (4 chunks of 64 W-rows) =================
    {
        const int mi_ = tid >> 4;     // M rows 4mi_..4mi_+3
        const int mj_ = tid & 15;     // M cols 4mj_..4mj_+3
        f32x4 mac[4];
        #pragma unroll
        for (int r = 0; r < 4; ++r) mac[r] = (f32x4){0.f, 0.f, 0.f, 0.f};
        for (int ch = 0; ch < 4; ++ch) {
            #pragma unroll
            for (int i = 0; i < 4; ++i) {
                int idx = tid + i * NTH;               // f32x4 index, 0..1023
                int kl = idx >> 4, c4 = (idx & 15) * 4;
                f32x4 v = *(const f32x4*)&Wg[(64 * ch + kl) * 64 + c4];
                *(f32x4*)(lds + WCo + kl * 256 + ((c4 * 4) ^ ((kl & 7) << 4))) = v;
            }
            __syncthreads();
            #pragma unroll 8
            for (int k = 0; k < 64; ++k) {
                f32x4 a = *(const f32x4*)(lds + WCo + k * 256 + ((mi_ * 16) ^ ((k & 7) << 4)));
                f32x4 b = *(const f32x4*)(lds + WCo + k * 256 + ((mj_ * 16) ^ ((k & 7) << 4)));
                #pragma unroll
                for (int r = 0; r < 4; ++r) mac[r] += b * a[r];
            }
            __syncthreads();          // WC chunk consumed (last iter: WC dead)
        }
        #pragma unroll
        for (int r = 0; r < 4; ++r) {
            int m = 4 * mi_ + r;
            *(f32x4*)(lds + Mo + m * 256 + ((mj_ * 16) ^ ((m & 7) << 4))) = mac[r];
        }
    }
    __syncthreads();

    // ====== power iteration on M (wave 0; M read from LDS) ======
    if (tid < 64) {
        const int xsw = (tid & 7) << 4;
        *(float*)(lds + Vo + tid * 4) = 0.125f;            // ones(64)/8
        for (int it = 0; it <= PITERS; ++it) {
            float a0 = 0.f, a1 = 0.f, a2 = 0.f, a3 = 0.f;
            #pragma unroll
            for (int q = 0; q < 4; ++q) {
                f32x4 m0 = *(const f32x4*)(lds + Mo + tid * 256 + (((4 * q + 0) * 16) ^ xsw));
                f32x4 m1 = *(const f32x4*)(lds + Mo + tid * 256 + (((4 * q + 1) * 16) ^ xsw));
                f32x4 m2 = *(const f32x4*)(lds + Mo + tid * 256 + (((4 * q + 2) * 16) ^ xsw));
                f32x4 m3 = *(const f32x4*)(lds + Mo + tid * 256 + (((4 * q + 3) * 16) ^ xsw));
                f32x4 v0 = *(const f32x4*)(lds + Vo + (4 * q + 0) * 16);
                f32x4 v1 = *(const f32x4*)(lds + Vo + (4 * q + 1) * 16);
                f32x4 v2 = *(const f32x4*)(lds + Vo + (4 * q + 2) * 16);
                f32x4 v3 = *(const f32x4*)(lds + Vo + (4 * q + 3) * 16);
                a0 += m0.x * v0.x + m0.y * v0.y + m0.z * v0.z + m0.w * v0.w;
                a1 += m1.x * v1.x + m1.y * v1.y + m1.z * v1.z + m1.w * v1.w;
                a2 += m2.x * v2.x + m2.y * v2.y + m2.z * v2.z + m2.w * v2.w;
                a3 += m3.x * v3.x + m3.y * v3.y + m3.z * v3.z + m3.w * v3.w;
            }
            float mv = (a0 + a1) + (a2 + a3);               // (M v)[tid]
            if (it < PITERS) {
                float n2 = mv * mv;
                #pragma unroll
                for (int off = 32; off >= 1; off >>= 1) n2 += __shfl_xor(n2, off);
                *(float*)(lds + Vo + tid * 4) = mv * (1.f / sqrtf(n2));
            } else {
                float pr = (*(const float*)(lds + Vo + tid * 4)) * mv;   // Rayleigh
                #pragma unroll
                for (int off = 32; off >= 1; off >>= 1) pr += __shfl_xor(pr, off);
                if (tid == 0) {
                    float L = 2.f * pr;                    // lambda(Q)=2*lambda(M)
                    scal[0] = 1.f / L;
                    scal[1] = LAMBDAV / L;
                }
            }
        }
    }
    __syncthreads();   // pow done; M/WC/v regions dead from here on

    const float c2  = 2.f * scal[0];
    const float thr = scal[1];

    // ---- p1 W frags (A-operand of swapped MFMA): 8 frags (32 VGPR) ----
    bf16x8 wbh[8];
    #pragma unroll
    for (int c = 0; c < 8; ++c) {
        bf16x8 ph{};
        #pragma unroll
        for (int t = 0; t < 8; ++t)
            ph[t] = (__bf16)Wg[(32 * c + 8 * l4 + t) * 64 + 16 * w + ln];
        wbh[c] = ph;
    }
    // ---- p2 A-hi frags: W[(4w+dt)*16+ln][kc*32+8l4+t] -> 8 frags (32 VGPR) --
    bf16x8 w2h[4][2];
    #pragma unroll
    for (int dt = 0; dt < 4; ++dt) {
        const int row = (4 * w + dt) * 16 + ln;
        #pragma unroll
        for (int kc = 0; kc < 2; ++kc) {
            f32x4 v0 = *(const f32x4*)&Wg[row * 64 + kc * 32 + 8 * l4];
            f32x4 v1 = *(const f32x4*)&Wg[row * 64 + kc * 32 + 8 * l4 + 4];
            bf16x8 p{};
            #pragma unroll
            for (int t = 0; t < 4; ++t) { p[t] = (__bf16)v0[t]; p[4 + t] = (__bf16)v1[t]; }
            w2h[dt][kc] = p;
        }
    }

    // ---- per-thread constants: -in in the R^T D-layout (f32x4 loads) ----
    float nin[2][4];
    #pragma unroll
    for (int s = 0; s < 2; ++s) {
        f32x4 iv = *(const f32x4*)&inp[(size_t)(rb + s * 16 + ln) * 64 + 16 * w + 4 * l4];
        #pragma unroll
        for (int r = 0; r < 4; ++r) nin[s][r] = -iv[r];
    }

    // ---- X0 -> xm/ym regs + y0-hi into YH (8 (dt,rt) tiles) ----
    float xm[4][2][4], ym[4][2][4];
    #pragma unroll
    for (int dt = 0; dt < 4; ++dt)
      #pragma unroll
      for (int rt = 0; rt < 2; ++rt) {
          f32x4 x = *(const f32x4*)&X0[(size_t)(rb + 16 * rt + ln) * 256 + (4 * w + dt) * 16 + 4 * l4];
          unsigned short hb[4];
          #pragma unroll
          for (int r = 0; r < 4; ++r) {
              xm[dt][rt][r] = x[r]; ym[dt][rt][r] = x[r];
              hb[r] = __builtin_bit_cast(unsigned short, (__bf16)x[r]);
          }
          const int row = 16 * rt + ln;
          const int off = row * 512 + ((((4 * w + dt) * 16 + 4 * l4) * 2) ^ rxl);
          uint2 H; H.x = hb[0] | ((unsigned)hb[1] << 16); H.y = hb[2] | ((unsigned)hb[3] << 16);
          *(uint2*)(lds + YHo + off) = H;
      }
    __syncthreads();

    float tt_ = 1.f;
    for (int step = 0; step < NSTEPS; ++step) {
        // ==== phase 1 (swapped): R^T = mfma(W-frag, y-frag); 4 acc chains ====
        f32x4 r0e = { nin[0][0], nin[0][1], nin[0][2], nin[0][3] };
        f32x4 r1e = { nin[1][0], nin[1][1], nin[1][2], nin[1][3] };
        f32x4 r0o = { 0.f, 0.f, 0.f, 0.f };
        f32x4 r1o = { 0.f, 0.f, 0.f, 0.f };
        #pragma unroll
        for (int c = 0; c < 8; ++c) {
            const int kb = c * 64 + l4 * 16;
            bf16x8 bh0 = *(const bf16x8*)(lds + YHo + ln * 512 + (kb ^ rxl));
            bf16x8 bh1 = *(const bf16x8*)(lds + YHo + (16 + ln) * 512 + (kb ^ rxl));
            if (c & 1) {
                r0o = __builtin_amdgcn_mfma_f32_16x16x32_bf16(wbh[c], bh0, r0o, 0, 0, 0);
                r1o = __builtin_amdgcn_mfma_f32_16x16x32_bf16(wbh[c], bh1, r1o, 0, 0, 0);
            } else {
                r0e = __builtin_amdgcn_mfma_f32_16x16x32_bf16(wbh[c], bh0, r0e, 0, 0, 0);
                r1e = __builtin_amdgcn_mfma_f32_16x16x32_bf16(wbh[c], bh1, r1e, 0, 0, 0);
            }
        }
        f32x4 acc0 = r0e + r0o;     // R[row ln][cols 16w+4l4 .. +3]
        f32x4 acc1 = r1e + r1o;
        #pragma unroll
        for (int s = 0; s < 2; ++s) {
            f32x4 v = s ? acc1 : acc0;
            unsigned short hb[4];
            #pragma unroll
            for (int r = 0; r < 4; ++r)
                hb[r] = __builtin_bit_cast(unsigned short, (__bf16)v[r]);
            const int row = s * 16 + ln;
            const int off = row * 128 + (((16 * w + 4 * l4) * 2) ^ ((row & 7) << 4));
            uint2 H; H.x = hb[0] | ((unsigned)hb[1] << 16); H.y = hb[2] | ((unsigned)hb[3] << 16);
            *(uint2*)(lds + RHo + off) = H;
        }
        __syncthreads();

        // ==== phase 2: g^T = Wh Rh^T (w2h in regs; only RH from LDS) ====
        f32x4 gt[4][2];
        #pragma unroll
        for (int dt = 0; dt < 4; ++dt)
            #pragma unroll
            for (int rt = 0; rt < 2; ++rt) gt[dt][rt] = (f32x4){0.f, 0.f, 0.f, 0.f};
        #pragma unroll
        for (int kc = 0; kc < 2; ++kc) {
            const int kb = kc * 64 + l4 * 16;
            bf16x8 bh[2];
            #pragma unroll
            for (int rt = 0; rt < 2; ++rt)
                bh[rt] = *(const bf16x8*)(lds + RHo + (16 * rt + ln) * 128 + (kb ^ rxl));
            #pragma unroll
            for (int dt = 0; dt < 4; ++dt)
                #pragma unroll
                for (int rt = 0; rt < 2; ++rt)
                    gt[dt][rt] = __builtin_amdgcn_mfma_f32_16x16x32_bf16(w2h[dt][kc], bh[rt], gt[dt][rt], 0, 0, 0);
        }

        // ==== update: prox + momentum (fp32 ym in regs); y-hi b64 writes ====
        const float t2v = 0.5f + 0.5f * sqrtf(1.f + 4.f * tt_ * tt_);
        const float mom = (tt_ - 1.f) / t2v;
        tt_ = t2v;
        #pragma unroll
        for (int dt = 0; dt < 4; ++dt)
          #pragma unroll
          for (int rt = 0; rt < 2; ++rt) {
              unsigned short hb[4];
              #pragma unroll
              for (int r = 0; r < 4; ++r) {
                  float u  = ym[dt][rt][r] - c2 * gt[dt][rt][r];
                  float x2 = u - fminf(fmaxf(u, -thr), thr);    // prox (exact)
                  float yn = x2 + mom * (x2 - xm[dt][rt][r]);
                  xm[dt][rt][r] = x2; ym[dt][rt][r] = yn;
                  hb[r] = __builtin_bit_cast(unsigned short, (__bf16)yn);
              }
              const int row = 16 * rt + ln;
              const int off = row * 512 + ((((4 * w + dt) * 16 + 4 * l4) * 2) ^ rxl);
              uint2 H; H.x = hb[0] | ((unsigned)hb[1] << 16); H.y = hb[2] | ((unsigned)hb[3] << 16);
              *(uint2*)(lds + YHo + off) = H;
          }
        __syncthreads();
    }

    // ---- store X (float4) ----
    #pragma unroll
    for (int dt = 0; dt < 4; ++dt)
      #pragma unroll
      for (int rt = 0; rt < 2; ++rt) {
          f32x4 o = { xm[dt][rt][0], xm[dt][rt][1], xm[dt][rt][2], xm[dt][rt][3] };
          *(f32x4*)&out[(size_t)(rb + 16 * rt + ln) * 256 + (4 * w + dt) * 16 + 4 * l4] = o;
      }
}

extern "C" void kernel_launch(void* const* d_in, const int* in_sizes, int n_in,
                              void* d_out, int out_size, void* d_ws, size_t ws_size,
                              hipStream_t stream) {
    (void)in_sizes; (void)n_in; (void)d_ws; (void)ws_size; (void)out_size;
    const float* inp = (const float*)d_in[0];   // [16384, 64]
    const float* Wg  = (const float*)d_in[1];   // [256, 64]
    const float* X0  = (const float*)d_in[2];   // [16384, 256]
    float* outp      = (float*)d_out;           // [16384, 256]
    fista19<<<16384 / ROWS, NTH, 0, stream>>>(inp, Wg, X0, outp);
}

// Round 21
// 225.850 us; speedup vs baseline: 1.0024x; 1.0024x over previous
//
#include <hip/hip_runtime.h>
#include <hip/hip_bf16.h>

#define NTH     128
#define ROWS    16
#define NSTEPS  100
#define PITERS  50
#define LAMBDAV 0.1f

typedef __bf16 bf16x8 __attribute__((ext_vector_type(8)));
typedef float  f32x4  __attribute__((ext_vector_type(4)));

// R21 = R20 geometry (NTH=128, ROWS=16, grid 1024 = 4 uniform blocks/CU)
// with the fp32 ym anchor RESTORED (R20's failure: bf16-quantized y anchor
// diverges ~O(n^2 * 2^-9) through the momentum recurrence -> absmax 2.8.
// Gradient-path quantization is attenuated; ANCHOR must stay fp32).
// Semantics identical to R18 -> absmax must be exactly 0.06640625.
// LDS map (16640 B, 4 blocks/CU = 66.5K):
//   YH bf16 [16][256] @0    (8192) stride 512
//   RH bf16 [16][64] @8192  (2048) stride 128
//   init overlays: WC/M fp32 [64][64] @0 (16384; dead before YH/RH use);
//   v fp32[64] @16384.
// Persistent regs ~200: wbh 64 + w2h 64 + xm 32 + ym 32 + nin 8.
// Spill signal = FETCH >> 10.6MB (then revert to R18).
#define YHo 0
#define RHo 8192
#define WCo 0
#define Mo  0
#define Vo  16384

__global__ __launch_bounds__(NTH, 2)
void fista21(const float* __restrict__ inp, const float* __restrict__ Wg,
             const float* __restrict__ X0, float* __restrict__ out)
{
    __shared__ __align__(16) char lds[16640];
    __shared__ float scal[2];

    const int tid  = threadIdx.x;
    const int w    = tid >> 6;        // 0..1
    const int lane = tid & 63;
    const int l4   = lane >> 4;       // 0..3
    const int ln   = lane & 15;       // 0..15
    const int rb   = blockIdx.x * ROWS;
    const int rxl  = (ln & 7) << 4;

    // ================= M = W^T W  (4 chunks of 64 W-rows) =================
    {
        const int mi_ = tid >> 4;     // 0..7 -> M rows 8mi_..8mi_+7
        const int mj_ = tid & 15;     // M cols 4mj_..4mj_+3
        f32x4 mac[8];
        #pragma unroll
        for (int r = 0; r < 8; ++r) mac[r] = (f32x4){0.f, 0.f, 0.f, 0.f};
        for (int ch = 0; ch < 4; ++ch) {
            #pragma unroll
            for (int i = 0; i < 8; ++i) {
                int idx = tid + i * NTH;               // f32x4 index, 0..1023
                int kl = idx >> 4, c4 = (idx & 15) * 4;
                f32x4 v = *(const f32x4*)&Wg[(64 * ch + kl) * 64 + c4];
                *(f32x4*)(lds + WCo + kl * 256 + ((c4 * 4) ^ ((kl & 7) << 4))) = v;
            }
            __syncthreads();
            #pragma unroll 8
            for (int k = 0; k < 64; ++k) {
                const int ks = (k & 7) << 4;
                f32x4 a0 = *(const f32x4*)(lds + WCo + k * 256 + ((mi_ * 32) ^ ks));
                f32x4 a1 = *(const f32x4*)(lds + WCo + k * 256 + ((mi_ * 32 + 16) ^ ks));
                f32x4 b  = *(const f32x4*)(lds + WCo + k * 256 + ((mj_ * 16) ^ ks));
                #pragma unroll
                for (int j = 0; j < 4; ++j) {
                    mac[j]     += b * a0[j];
                    mac[4 + j] += b * a1[j];
                }
            }
            __syncthreads();          // WC chunk consumed (last iter: WC dead)
        }
        #pragma unroll
        for (int j = 0; j < 8; ++j) {
            int m = 8 * mi_ + j;
            *(f32x4*)(lds + Mo + m * 256 + ((mj_ * 16) ^ ((m & 7) << 4))) = mac[j];
        }
    }
    __syncthreads();

    // ====== power iteration on M (wave 0; M read from LDS) ======
    if (tid < 64) {
        const int xsw = (tid & 7) << 4;
        *(float*)(lds + Vo + tid * 4) = 0.125f;            // ones(64)/8
        for (int it = 0; it <= PITERS; ++it) {
            float a0 = 0.f, a1 = 0.f, a2 = 0.f, a3 = 0.f;
            #pragma unroll
            for (int q = 0; q < 4; ++q) {
                f32x4 m0 = *(const f32x4*)(lds + Mo + tid * 256 + (((4 * q + 0) * 16) ^ xsw));
                f32x4 m1 = *(const f32x4*)(lds + Mo + tid * 256 + (((4 * q + 1) * 16) ^ xsw));
                f32x4 m2 = *(const f32x4*)(lds + Mo + tid * 256 + (((4 * q + 2) * 16) ^ xsw));
                f32x4 m3 = *(const f32x4*)(lds + Mo + tid * 256 + (((4 * q + 3) * 16) ^ xsw));
                f32x4 v0 = *(const f32x4*)(lds + Vo + (4 * q + 0) * 16);
                f32x4 v1 = *(const f32x4*)(lds + Vo + (4 * q + 1) * 16);
                f32x4 v2 = *(const f32x4*)(lds + Vo + (4 * q + 2) * 16);
                f32x4 v3 = *(const f32x4*)(lds + Vo + (4 * q + 3) * 16);
                a0 += m0.x * v0.x + m0.y * v0.y + m0.z * v0.z + m0.w * v0.w;
                a1 += m1.x * v1.x + m1.y * v1.y + m1.z * v1.z + m1.w * v1.w;
                a2 += m2.x * v2.x + m2.y * v2.y + m2.z * v2.z + m2.w * v2.w;
                a3 += m3.x * v3.x + m3.y * v3.y + m3.z * v3.z + m3.w * v3.w;
            }
            float mv = (a0 + a1) + (a2 + a3);               // (M v)[tid]
            if (it < PITERS) {
                float n2 = mv * mv;
                #pragma unroll
                for (int off = 32; off >= 1; off >>= 1) n2 += __shfl_xor(n2, off);
                *(float*)(lds + Vo + tid * 4) = mv * (1.f / sqrtf(n2));
            } else {
                float pr = (*(const float*)(lds + Vo + tid * 4)) * mv;   // Rayleigh
                #pragma unroll
                for (int off = 32; off >= 1; off >>= 1) pr += __shfl_xor(pr, off);
                if (tid == 0) {
                    float L = 2.f * pr;                    // lambda(Q)=2*lambda(M)
                    scal[0] = 1.f / L;
                    scal[1] = LAMBDAV / L;
                }
            }
        }
    }
    __syncthreads();   // pow done; M/WC/v regions dead from here on

    const float c2  = 2.f * scal[0];
    const float thr = scal[1];

    // ---- p1 W frags (A-operand, n-tiles {2w, 2w+1}): 16 frags (64 VGPR) ----
    bf16x8 wbh[2][8];
    #pragma unroll
    for (int q = 0; q < 2; ++q)
        #pragma unroll
        for (int c = 0; c < 8; ++c) {
            bf16x8 ph{};
            #pragma unroll
            for (int t = 0; t < 8; ++t)
                ph[t] = (__bf16)Wg[(32 * c + 8 * l4 + t) * 64 + (2 * w + q) * 16 + ln];
            wbh[q][c] = ph;
        }
    // ---- p2 A-hi frags (dout-tiles 8w..8w+7): 16 frags (64 VGPR) ----
    bf16x8 w2h[8][2];
    #pragma unroll
    for (int dt = 0; dt < 8; ++dt) {
        const int row = (8 * w + dt) * 16 + ln;
        #pragma unroll
        for (int kc = 0; kc < 2; ++kc) {
            f32x4 v0 = *(const f32x4*)&Wg[row * 64 + kc * 32 + 8 * l4];
            f32x4 v1 = *(const f32x4*)&Wg[row * 64 + kc * 32 + 8 * l4 + 4];
            bf16x8 p{};
            #pragma unroll
            for (int t = 0; t < 4; ++t) { p[t] = (__bf16)v0[t]; p[4 + t] = (__bf16)v1[t]; }
            w2h[dt][kc] = p;
        }
    }

    // ---- per-thread constants: -in in the R^T D-layout (f32x4 loads) ----
    float nin[2][4];
    #pragma unroll
    for (int q = 0; q < 2; ++q) {
        f32x4 iv = *(const f32x4*)&inp[(size_t)(rb + ln) * 64 + (2 * w + q) * 16 + 4 * l4];
        #pragma unroll
        for (int r = 0; r < 4; ++r) nin[q][r] = -iv[r];
    }

    // ---- X0 -> xm/ym regs + y0-hi into YH (8 dt tiles) ----
    float xm[8][4], ym[8][4];
    #pragma unroll
    for (int dt = 0; dt < 8; ++dt) {
        f32x4 x = *(const f32x4*)&X0[(size_t)(rb + ln) * 256 + (8 * w + dt) * 16 + 4 * l4];
        unsigned short hb[4];
        #pragma unroll
        for (int r = 0; r < 4; ++r) {
            xm[dt][r] = x[r]; ym[dt][r] = x[r];
            hb[r] = __builtin_bit_cast(unsigned short, (__bf16)x[r]);
        }
        const int off = ln * 512 + ((((8 * w + dt) * 16 + 4 * l4) * 2) ^ rxl);
        uint2 H; H.x = hb[0] | ((unsigned)hb[1] << 16); H.y = hb[2] | ((unsigned)hb[3] << 16);
        *(uint2*)(lds + YHo + off) = H;
    }
    __syncthreads();

    float tt_ = 1.f;
    for (int step = 0; step < NSTEPS; ++step) {
        // ==== phase 1 (swapped): R^T = mfma(W-frag, y-frag); 4 acc chains ====
        f32x4 r0e = { nin[0][0], nin[0][1], nin[0][2], nin[0][3] };
        f32x4 r1e = { nin[1][0], nin[1][1], nin[1][2], nin[1][3] };
        f32x4 r0o = { 0.f, 0.f, 0.f, 0.f };
        f32x4 r1o = { 0.f, 0.f, 0.f, 0.f };
        #pragma unroll
        for (int c = 0; c < 8; ++c) {
            const int kb = c * 64 + l4 * 16;
            bf16x8 bh = *(const bf16x8*)(lds + YHo + ln * 512 + (kb ^ rxl));
            if (c & 1) {
                r0o = __builtin_amdgcn_mfma_f32_16x16x32_bf16(wbh[0][c], bh, r0o, 0, 0, 0);
                r1o = __builtin_amdgcn_mfma_f32_16x16x32_bf16(wbh[1][c], bh, r1o, 0, 0, 0);
            } else {
                r0e = __builtin_amdgcn_mfma_f32_16x16x32_bf16(wbh[0][c], bh, r0e, 0, 0, 0);
                r1e = __builtin_amdgcn_mfma_f32_16x16x32_bf16(wbh[1][c], bh, r1e, 0, 0, 0);
            }
        }
        f32x4 acc0 = r0e + r0o;     // R[row ln][cols (2w+0)*16 + 4l4 .. +3]
        f32x4 acc1 = r1e + r1o;
        #pragma unroll
        for (int q = 0; q < 2; ++q) {
            f32x4 v = q ? acc1 : acc0;
            unsigned short hb[4];
            #pragma unroll
            for (int r = 0; r < 4; ++r)
                hb[r] = __builtin_bit_cast(unsigned short, (__bf16)v[r]);
            const int off = ln * 128 + ((((2 * w + q) * 16 + 4 * l4) * 2) ^ rxl);
            uint2 H; H.x = hb[0] | ((unsigned)hb[1] << 16); H.y = hb[2] | ((unsigned)hb[3] << 16);
            *(uint2*)(lds + RHo + off) = H;
        }
        __syncthreads();

        // ==== phase 2: g^T = Wh Rh^T (w2h in regs; 2 RH reads) ====
        f32x4 gt[8];
        #pragma unroll
        for (int dt = 0; dt < 8; ++dt) gt[dt] = (f32x4){0.f, 0.f, 0.f, 0.f};
        #pragma unroll
        for (int kc = 0; kc < 2; ++kc) {
            const int kb = kc * 64 + l4 * 16;
            bf16x8 bh = *(const bf16x8*)(lds + RHo + ln * 128 + (kb ^ rxl));
            #pragma unroll
            for (int dt = 0; dt < 8; ++dt)
                gt[dt] = __builtin_amdgcn_mfma_f32_16x16x32_bf16(w2h[dt][kc], bh, gt[dt], 0, 0, 0);
        }

        // ==== update: prox + momentum (fp32 ym anchor); y-hi b64 writes ====
        const float t2v = 0.5f + 0.5f * sqrtf(1.f + 4.f * tt_ * tt_);
        const float mom = (tt_ - 1.f) / t2v;
        tt_ = t2v;
        #pragma unroll
        for (int dt = 0; dt < 8; ++dt) {
            unsigned short hb[4];
            #pragma unroll
            for (int r = 0; r < 4; ++r) {
                float u  = ym[dt][r] - c2 * gt[dt][r];
                float x2 = u - fminf(fmaxf(u, -thr), thr);    // prox (exact)
                float yn = x2 + mom * (x2 - xm[dt][r]);
                xm[dt][r] = x2; ym[dt][r] = yn;
                hb[r] = __builtin_bit_cast(unsigned short, (__bf16)yn);
            }
            const int off = ln * 512 + ((((8 * w + dt) * 16 + 4 * l4) * 2) ^ rxl);
            uint2 H; H.x = hb[0] | ((unsigned)hb[1] << 16); H.y = hb[2] | ((unsigned)hb[3] << 16);
            *(uint2*)(lds + YHo + off) = H;
        }
        __syncthreads();
    }

    // ---- store X (float4) ----
    #pragma unroll
    for (int dt = 0; dt < 8; ++dt) {
        f32x4 o = { xm[dt][0], xm[dt][1], xm[dt][2], xm[dt][3] };
        *(f32x4*)&out[(size_t)(rb + ln) * 256 + (8 * w + dt) * 16 + 4 * l4] = o;
    }
}

extern "C" void kernel_launch(void* const* d_in, const int* in_sizes, int n_in,
                              void* d_out, int out_size, void* d_ws, size_t ws_size,
                              hipStream_t stream) {
    (void)in_sizes; (void)n_in; (void)d_ws; (void)ws_size; (void)out_size;
    const float* inp = (const float*)d_in[0];   // [16384, 64]
    const float* Wg  = (const float*)d_in[1];   // [256, 64]
    const float* X0  = (const float*)d_in[2];   // [16384, 256]
    float* outp      = (float*)d_out;           // [16384, 256]
    fista21<<<16384 / ROWS, NTH, 0, stream>>>(inp, Wg, X0, outp);
}